// Round 22
// baseline (114.094 us; speedup 1.0000x reference)
//
#include <hip/hip_runtime.h>
#include <hip/hip_bf16.h>

// InfoNCE loss, N=8192 D=512 C=128.
// Fixed-shift softmax (M=10): t_ij = s_ij/tau - 10 in [-20, 0].
//   Z_i  = sum_{class!=} e^{t_ij}
//   term = -t_p + log(Z + e^{t_p}) ~= -t_p + logZ + e^{t_p}/Z
// r21 -> r22: retry r20's barrier-free direct-from-L2 GEMM with the
// diagnosed ILP bug fixed: B fragments DOUBLE-BUFFERED in registers
// (b0/b1, compile-time selected via macro-unrolled steps) so the 8 loads
// for window kf+1 are in flight while kf's 16 MFMAs run. r20 failed
// because load->immediate-use serialized every MFMA behind ~250cy L2
// latency (VGPR 76 = nothing in flight). No LDS staging, no barriers,
// no vmcnt asm. areg 64 + acc 64 + b 32 ~= 200 regs -> 2 waves/SIMD,
// mutual interleave covers residual latency. Tail kernels = r21 verbatim.

constexpr int   D      = 512;
constexpr int   BT     = 128;
constexpr float SHIFTL = 14.4269504088896340f;        // 10 * log2(e)
constexpr float QS2L   = 10.0f * 1.4426950408889634f / 16129.0f; // /tau/127^2*log2e
constexpr float LN2    = 0.6931471805599453f;

typedef __attribute__((ext_vector_type(4))) int i32x4;
typedef unsigned char uchar;
typedef unsigned long ulong_t;

// ---------------- K1: L2-normalize rows, f32 -> i8 (+hist in block 0) ----
__global__ void k_normalize(const float* __restrict__ emb,
                            const int* __restrict__ classes,
                            uchar* __restrict__ normed,
                            int* __restrict__ hist, int n) {
    if (blockIdx.x == 0) {
        __shared__ int h[128];
        if (threadIdx.x < 128) h[threadIdx.x] = 0;
        __syncthreads();
        for (int i = threadIdx.x; i < n; i += 256)
            atomicAdd(&h[classes[i] & 127], 1);
        __syncthreads();
        if (threadIdx.x < 128) hist[threadIdx.x] = h[threadIdx.x];
    }
    int row  = blockIdx.x * 4 + (threadIdx.x >> 6);
    int lane = threadIdx.x & 63;
    if (row >= n) return;
    const float4* src = (const float4*)(emb + (size_t)row * D);
    float4 a = src[lane * 2];
    float4 b = src[lane * 2 + 1];
    float ss = a.x*a.x + a.y*a.y + a.z*a.z + a.w*a.w
             + b.x*b.x + b.y*b.y + b.z*b.z + b.w*b.w;
#pragma unroll
    for (int m = 1; m < 64; m <<= 1) ss += __shfl_xor(ss, m, 64);
    float sc = 127.0f / fmaxf(sqrtf(ss), 1e-12f);
    union { signed char c[8]; ulong_t u; } o;
    float v[8] = {a.x, a.y, a.z, a.w, b.x, b.y, b.z, b.w};
#pragma unroll
    for (int k = 0; k < 8; ++k) {
        int q = (int)rintf(v[k] * sc);
        q = q > 127 ? 127 : (q < -127 ? -127 : q);
        o.c[k] = (signed char)q;
    }
    *(ulong_t*)&normed[(size_t)row * D + lane * 8] = o.u;
}

// ---------------- K2: barrier-free i8 GEMM, A-regs + B reg-prefetch -------
// Zpart: plane q in 0..2 (Z,NS2,P1), each [64 slots][n rows].
__global__ __launch_bounds__(256, 2) void k_zgemm(
    const uchar* __restrict__ normed, const int* __restrict__ classes,
    float* __restrict__ Zpart, int n, int nb, int npairs) {
    __shared__ float redr[BT * 3];            // 1.5 KB
    __shared__ float redc[4 * BT * 3];        // 6 KB
    __shared__ int clsrow[BT], clscol[BT];

    const int tid  = threadIdx.x;
    const int lane = tid & 63;
    const int w    = tid >> 6;                // wave owns rows w*32..+32
    const int l15  = lane & 15, l4 = lane >> 4;
    const size_t QS = (size_t)64 * n;

    // XCD-chunked bijective swizzle
    int q8 = npairs >> 3, r8 = npairs & 7;
    int xcd = blockIdx.x & 7, off = blockIdx.x >> 3;
    int orig = (xcd < r8 ? xcd * (q8 + 1) : r8 * (q8 + 1) + (xcd - r8) * q8) + off;

    // orig -> (bi,bj) via 8x8 supertile walk (L2 locality within an XCD)
    const int sgrid = nb >> 3;               // 8
    int idx = orig, si = 0;
    for (;;) { int rc = 36 + (sgrid - 1 - si) * 64; if (idx < rc) break; idx -= rc; ++si; }
    int bi, bj;
    if (idx < 36) { int u = 0, rem = 8; while (idx >= rem) { idx -= rem; ++u; --rem; }
                    bi = si * 8 + u; bj = si * 8 + u + idx; }
    else { idx -= 36; int sj = si + 1 + (idx >> 6); int v = idx & 63;
           bi = si * 8 + (v >> 3); bj = sj * 8 + (v & 7); }
    const int row0 = bi * BT, c0 = bj * BT;
    const bool diagblk = (bi == bj);

    if (tid < BT) clsrow[tid] = classes[row0 + tid];
    else          clscol[tid - BT] = classes[c0 + tid - BT];

    // ---- A strip into registers ----
    i32x4 areg[2][8];
#pragma unroll
    for (int rg = 0; rg < 2; ++rg)
#pragma unroll
        for (int kf = 0; kf < 8; ++kf)
            areg[rg][kf] = *(const i32x4*)&normed[
                (size_t)(row0 + w * 32 + rg * 16 + l15) * D + kf * 64 + l4 * 16];

    // ---- B: double-buffered register prefetch, barrier-free ----
    const uchar* bbase = normed + (size_t)c0 * D + (size_t)l15 * D + l4 * 16;
    // fragment address for (kf, cf): bbase + cf*16*D + kf*64
#define BADDR(KF, CF) ((const i32x4*)(bbase + (size_t)(CF) * 16 * D + (KF) * 64))

    i32x4 acc[2][8];
#pragma unroll
    for (int rg = 0; rg < 2; ++rg)
#pragma unroll
        for (int cf = 0; cf < 8; ++cf) acc[rg][cf] = (i32x4){0, 0, 0, 0};

    i32x4 b0[8], b1[8];
#pragma unroll
    for (int cf = 0; cf < 8; ++cf) b0[cf] = *BADDR(0, cf);

#define STEP(KF, BCUR, BNXT)                                                   \
    if ((KF) + 1 < 8) {                                                        \
        _Pragma("unroll") for (int cf = 0; cf < 8; ++cf)                       \
            BNXT[cf] = *BADDR((KF) + 1, cf);                                   \
    }                                                                          \
    __builtin_amdgcn_s_setprio(1);                                             \
    _Pragma("unroll") for (int cf = 0; cf < 8; ++cf) {                         \
        acc[0][cf] = __builtin_amdgcn_mfma_i32_16x16x64_i8(                    \
            areg[0][KF], BCUR[cf], acc[0][cf], 0, 0, 0);                       \
        acc[1][cf] = __builtin_amdgcn_mfma_i32_16x16x64_i8(                    \
            areg[1][KF], BCUR[cf], acc[1][cf], 0, 0, 0);                       \
    }                                                                          \
    __builtin_amdgcn_s_setprio(0);

    STEP(0, b0, b1) STEP(1, b1, b0) STEP(2, b0, b1) STEP(3, b1, b0)
    STEP(4, b0, b1) STEP(5, b1, b0) STEP(6, b0, b1) STEP(7, b1, b0)
#undef STEP
#undef BADDR

    // ---- epilogue (exp2 domain), r19/r21 layout ----
    int crow[2][4];
#pragma unroll
    for (int rg = 0; rg < 2; ++rg)
#pragma unroll
        for (int r = 0; r < 4; ++r)
            crow[rg][r] = clsrow[w * 32 + rg * 16 + l4 * 4 + r];
    int ccv[8];
#pragma unroll
    for (int cf = 0; cf < 8; ++cf) ccv[cf] = clscol[cf * 16 + l15];

    float cq[8][3];
#pragma unroll
    for (int cf = 0; cf < 8; ++cf) cq[cf][0] = cq[cf][1] = cq[cf][2] = 0.f;

#pragma unroll
    for (int rg = 0; rg < 2; ++rg) {
#pragma unroll
        for (int r = 0; r < 4; ++r) {
            int rr = w * 32 + rg * 16 + l4 * 4 + r;
            int cr = crow[rg][r];
            float z = 0.f, ns = 0.f, p1 = 0.f;
#pragma unroll
            for (int cf = 0; cf < 8; ++cf) {
                int cc = cf * 16 + l15;
                float tt = fmaf((float)acc[rg][cf][r], QS2L, -SHIFTL);
                float e = exp2f(tt);
                bool same = (cr == ccv[cf]);
                bool dg   = diagblk && (rr == cc);
                if (!same) { z += e; cq[cf][0] += e; }
                else if (!dg) { ns += tt; p1 += e; cq[cf][1] += tt; cq[cf][2] += e; }
            }
#pragma unroll
            for (int m = 1; m < 16; m <<= 1) {
                z  += __shfl_xor(z,  m, 16);
                ns += __shfl_xor(ns, m, 16);
                p1 += __shfl_xor(p1, m, 16);
            }
            if (l15 == 0) {
                redr[rr * 3 + 0] = z;
                redr[rr * 3 + 1] = ns;
                redr[rr * 3 + 2] = p1;
            }
        }
    }
    if (!diagblk) {
#pragma unroll
        for (int cf = 0; cf < 8; ++cf) {
            float z = cq[cf][0], nsv = cq[cf][1], p = cq[cf][2];
            z += __shfl_xor(z, 16, 64);  z += __shfl_xor(z, 32, 64);
            nsv += __shfl_xor(nsv, 16, 64); nsv += __shfl_xor(nsv, 32, 64);
            p += __shfl_xor(p, 16, 64);  p += __shfl_xor(p, 32, 64);
            if (l4 == 0) {
                float* pp = &redc[(w * 128 + cf * 16 + l15) * 3];
                pp[0] = z; pp[1] = nsv; pp[2] = p;
            }
        }
    }
    __syncthreads();

    if (tid < BT) {                           // row-side partials, slot = bj
#pragma unroll
        for (int q = 0; q < 3; ++q)
            Zpart[q * QS + (size_t)bj * n + row0 + tid] = redr[tid * 3 + q];
    } else if (!diagblk) {                    // col-side partials, slot = bi
        int cc = tid - BT;
#pragma unroll
        for (int q = 0; q < 3; ++q)
            Zpart[q * QS + (size_t)bi * n + c0 + cc] =
                redc[(0 * 128 + cc) * 3 + q] + redc[(1 * 128 + cc) * 3 + q] +
                redc[(2 * 128 + cc) * 3 + q] + redc[(3 * 128 + cc) * 3 + q];
    }
}

// ---------------- K3: per-row terms -> per-block (loss,cnt) partials ------
__global__ void k_rowterms(const float* __restrict__ Zpart,
                           const int* __restrict__ classes,
                           const int* __restrict__ hist,
                           float* __restrict__ partial, int n) {
    const int tid = threadIdx.x;
    const int i   = blockIdx.x * 128 + tid;
    const size_t QS = (size_t)64 * n;
    float z = 0.f, ns = 0.f, p1 = 0.f;
    for (int s = 0; s < 64; ++s) {
        size_t o = (size_t)s * n + i;
        z  += Zpart[o];
        ns += Zpart[QS + o];
        p1 += Zpart[2 * QS + o];
    }
    float c    = (float)(hist[classes[i] & 127] - 1);
    float loss = -ns * LN2 + c * logf(z) + p1 / z;   // ns was in log2 units

    __shared__ float sl[2], sc[2];
    float L = loss, C = c;
#pragma unroll
    for (int m = 1; m < 64; m <<= 1) {
        L += __shfl_xor(L, m, 64);
        C += __shfl_xor(C, m, 64);
    }
    if ((tid & 63) == 0) { sl[tid >> 6] = L; sc[tid >> 6] = C; }
    __syncthreads();
    if (tid == 0) {
        partial[blockIdx.x * 2]     = sl[0] + sl[1];
        partial[blockIdx.x * 2 + 1] = sc[0] + sc[1];
    }
}

// ---------------- K4: final reduction of 64 partial pairs ----------------
__global__ void k_final(const float* __restrict__ partial,
                        float* __restrict__ out) {
    int lane = threadIdx.x;                   // one wave
    float L = partial[lane * 2];
    float C = partial[lane * 2 + 1];
#pragma unroll
    for (int m = 1; m < 64; m <<= 1) {
        L += __shfl_xor(L, m, 64);
        C += __shfl_xor(C, m, 64);
    }
    if (lane == 0) out[0] = (C > 0.f) ? L / C : 0.f;
}

extern "C" void kernel_launch(void* const* d_in, const int* in_sizes, int n_in,
                              void* d_out, int out_size, void* d_ws, size_t ws_size,
                              hipStream_t stream) {
    const float* emb     = (const float*)d_in[0];
    const int*   classes = (const int*)d_in[1];
    float*       out     = (float*)d_out;
    const int n  = in_sizes[1];               // 8192
    const int nb = n / BT;                    // 64
    const int npairs = nb * (nb + 1) / 2;     // 2080

    uchar*  normed  = (uchar*)d_ws;                                    // 4 MB
    float*  Zpart   = (float*)((char*)d_ws + (size_t)n * D);           // 6 MB
    float*  partial = Zpart + (size_t)3 * 64 * n;                      // 128 floats
    int*    hist    = (int*)(partial + 128);                           // 512 B

    k_normalize<<<n / 4, 256, 0, stream>>>(emb, classes, normed, hist, n);
    k_zgemm<<<npairs, 256, 0, stream>>>(normed, classes, Zpart, n, nb, npairs);
    k_rowterms<<<n / 128, 128, 0, stream>>>(Zpart, classes, hist, partial, n);
    k_final<<<1, 64, 0, stream>>>(partial, out);
}

// Round 23
// 73.347 us; speedup vs baseline: 1.5555x; 1.5555x over previous
//
#include <hip/hip_runtime.h>
#include <hip/hip_bf16.h>

// InfoNCE loss, N=8192 D=512 C=128.
// Fixed-shift softmax (M=10): t_ij = s_ij/tau - 10 in [-20, 0].
//   Z_i  = sum_{class!=} e^{t_ij}
//   term = -t_p + log(Z + e^{t_p}) ~= -t_p + logZ + e^{t_p}/Z
// r22 -> r23: RESTORE r21 (best measured: 73.7us total). r22's register
// double-buffer retry failed identically to r20 (VGPR 104 -> compiler
// rematerialized loads next to uses; MfmaUtil 7%). Eleven zgemm structures
// bracket the space: all LDS-staged barriered variants converge to
// 52.7-52.9us; all escapes regressed. r21 = A-in-regs + B ring-3 + BK=128 +
// counted vmcnt zgemm, 64-block rowterms with block-reduce, 1-wave final.

constexpr int   D      = 512;
constexpr int   BT     = 128;
constexpr int   BK     = 128;        // bytes (i8 elems) per window
constexpr int   NSTEP  = D / BK;     // 4
constexpr float SHIFTL = 14.4269504088896340f;        // 10 * log2(e)
constexpr float QS2L   = 10.0f * 1.4426950408889634f / 16129.0f; // /tau/127^2*log2e
constexpr float LN2    = 0.6931471805599453f;

typedef __attribute__((ext_vector_type(4))) int i32x4;
typedef unsigned char uchar;
typedef unsigned long ulong_t;

__device__ inline void gload_lds16(const uchar* g, void* l) {
    __builtin_amdgcn_global_load_lds(
        (const __attribute__((address_space(1))) void*)g,
        (__attribute__((address_space(3))) void*)l, 16, 0, 0);
}

// ---------------- K1: L2-normalize rows, f32 -> i8 (+hist in block 0) ----
__global__ void k_normalize(const float* __restrict__ emb,
                            const int* __restrict__ classes,
                            uchar* __restrict__ normed,
                            int* __restrict__ hist, int n) {
    if (blockIdx.x == 0) {
        __shared__ int h[128];
        if (threadIdx.x < 128) h[threadIdx.x] = 0;
        __syncthreads();
        for (int i = threadIdx.x; i < n; i += 256)
            atomicAdd(&h[classes[i] & 127], 1);
        __syncthreads();
        if (threadIdx.x < 128) hist[threadIdx.x] = h[threadIdx.x];
    }
    int row  = blockIdx.x * 4 + (threadIdx.x >> 6);
    int lane = threadIdx.x & 63;
    if (row >= n) return;
    const float4* src = (const float4*)(emb + (size_t)row * D);
    float4 a = src[lane * 2];
    float4 b = src[lane * 2 + 1];
    float ss = a.x*a.x + a.y*a.y + a.z*a.z + a.w*a.w
             + b.x*b.x + b.y*b.y + b.z*b.z + b.w*b.w;
#pragma unroll
    for (int m = 1; m < 64; m <<= 1) ss += __shfl_xor(ss, m, 64);
    float sc = 127.0f / fmaxf(sqrtf(ss), 1e-12f);
    union { signed char c[8]; ulong_t u; } o;
    float v[8] = {a.x, a.y, a.z, a.w, b.x, b.y, b.z, b.w};
#pragma unroll
    for (int k = 0; k < 8; ++k) {
        int q = (int)rintf(v[k] * sc);
        q = q > 127 ? 127 : (q < -127 ? -127 : q);
        o.c[k] = (signed char)q;
    }
    *(ulong_t*)&normed[(size_t)row * D + lane * 8] = o.u;
}

// ---------------- K2: i8 GEMM, A-in-regs + B ring-3, BK=128 (r19) ---------
// Zpart: plane q in 0..2 (Z,NS2,P1), each [64 slots][n rows].
__global__ __launch_bounds__(256, 3) void k_zgemm(
    const uchar* __restrict__ normed, const int* __restrict__ classes,
    float* __restrict__ Zpart, int n, int nb, int npairs) {
    __shared__ char ring[3][16384];           // B-only: 3 windows x 16KB
    __shared__ int clsrow[BT], clscol[BT];

    const int tid  = threadIdx.x;
    const int lane = tid & 63;
    const int w    = tid >> 6;                // wave owns rows w*32..+32
    const int l15  = lane & 15, l4 = lane >> 4;
    const size_t QS = (size_t)64 * n;

    // XCD-chunked bijective swizzle
    int q8 = npairs >> 3, r8 = npairs & 7;
    int xcd = blockIdx.x & 7, off = blockIdx.x >> 3;
    int orig = (xcd < r8 ? xcd * (q8 + 1) : r8 * (q8 + 1) + (xcd - r8) * q8) + off;

    // orig -> (bi,bj) via 8x8 supertile walk
    const int sgrid = nb >> 3;               // 8
    int idx = orig, si = 0;
    for (;;) { int rc = 36 + (sgrid - 1 - si) * 64; if (idx < rc) break; idx -= rc; ++si; }
    int bi, bj;
    if (idx < 36) { int u = 0, rem = 8; while (idx >= rem) { idx -= rem; ++u; --rem; }
                    bi = si * 8 + u; bj = si * 8 + u + idx; }
    else { idx -= 36; int sj = si + 1 + (idx >> 6); int v = idx & 63;
           bi = si * 8 + (v >> 3); bj = sj * 8 + (v & 7); }
    const int row0 = bi * BT, c0 = bj * BT;
    const bool diagblk = (bi == bj);

    if (tid < BT) clsrow[tid] = classes[row0 + tid];
    else          clscol[tid - BT] = classes[c0 + tid - BT];

    // ---- A strip into registers (issued FIRST; drained by prologue wait) --
    i32x4 areg[2][8];
#pragma unroll
    for (int rg = 0; rg < 2; ++rg)
#pragma unroll
        for (int kf = 0; kf < 8; ++kf)
            areg[rg][kf] = *(const i32x4*)&normed[
                (size_t)(row0 + w * 32 + rg * 16 + l15) * D + kf * 64 + l4 * 16];

    // B staging: per 8KB half = 8 chunks of 16 cols x 64B; wave w owns
    // chunks {2w,2w+1}. Source 16B slot pre-swizzled (involution, r10).
    const int src16 = (lane & 3) ^ ((lane >> 3) & 3);
    size_t gB[2]; int lo[2];
#pragma unroll
    for (int it = 0; it < 2; ++it) {
        int chunk = w * 2 + it;
        int row   = chunk * 16 + (lane >> 2);
        gB[it] = (size_t)(c0 + row) * D + src16 * 16;
        lo[it] = chunk * 1024;
    }
    char* ringb = &ring[0][0];

    auto STAGE = [&](int sbo, int kk) {       // kk = window * 128 (bytes)
#pragma unroll
        for (int h = 0; h < 2; ++h)
#pragma unroll
            for (int it = 0; it < 2; ++it)
                gload_lds16(normed + gB[it] + kk + h * 64,
                            ringb + sbo + h * 8192 + lo[it]);
    };

    i32x4 acc[2][8];
#pragma unroll
    for (int rg = 0; rg < 2; ++rg)
#pragma unroll
        for (int cf = 0; cf < 8; ++cf) acc[rg][cf] = (i32x4){0, 0, 0, 0};

    STAGE(0, 0);
    STAGE(16384, BK);
    __builtin_amdgcn_sched_barrier(0);
    asm volatile("s_waitcnt vmcnt(4) lgkmcnt(0)" ::: "memory");
    __builtin_amdgcn_s_barrier();
    __builtin_amdgcn_sched_barrier(0);

    // b128 B read: 16B slot = l4 ^ ((rb>>1)&3), rb>>1 ~ l15>>1 (0 conflicts)
    const int rsw = (l15 >> 1) & 3;

#pragma unroll
    for (int kt = 0; kt < NSTEP; ++kt) {
        const int cur = kt % 3;
        if (kt + 2 < NSTEP) STAGE(((kt + 2) % 3) * 16384, (kt + 2) * BK);
        const char* base = ringb + cur * 16384;
#pragma unroll
        for (int h = 0; h < 2; ++h) {
            const char* lb = base + h * 8192;
            i32x4 bfr[8];
#pragma unroll
            for (int cf = 0; cf < 8; ++cf) {
                int rb = cf * 16 + l15;
                bfr[cf] = *(const i32x4*)(lb + rb * 64 + ((l4 ^ rsw) << 4));
            }
            __builtin_amdgcn_s_setprio(1);
#pragma unroll
            for (int rg = 0; rg < 2; ++rg)
#pragma unroll
                for (int cf = 0; cf < 8; ++cf)
                    acc[rg][cf] = __builtin_amdgcn_mfma_i32_16x16x64_i8(
                        areg[rg][kt * 2 + h], bfr[cf], acc[rg][cf], 0, 0, 0);
            __builtin_amdgcn_s_setprio(0);
        }
        __builtin_amdgcn_sched_barrier(0);
        if (kt + 2 < NSTEP)       asm volatile("s_waitcnt vmcnt(4)" ::: "memory");
        else if (kt + 2 == NSTEP) asm volatile("s_waitcnt vmcnt(0)" ::: "memory");
        if (kt + 1 < NSTEP) {
            __builtin_amdgcn_s_barrier();
            __builtin_amdgcn_sched_barrier(0);
        }
    }
    __syncthreads();   // full drain before LDS overlay

    // ---- epilogue (exp2 domain): r17/r19 layout ----
    float* redr = (float*)ringb;              // [128 rr][3] = 1.5 KB
    float* redc = (float*)(ringb + 2048);     // [4 w][128 cc][3] = 6 KB

    int crow[2][4];
#pragma unroll
    for (int rg = 0; rg < 2; ++rg)
#pragma unroll
        for (int r = 0; r < 4; ++r)
            crow[rg][r] = clsrow[w * 32 + rg * 16 + l4 * 4 + r];
    int ccv[8];
#pragma unroll
    for (int cf = 0; cf < 8; ++cf) ccv[cf] = clscol[cf * 16 + l15];

    float cq[8][3];
#pragma unroll
    for (int cf = 0; cf < 8; ++cf) cq[cf][0] = cq[cf][1] = cq[cf][2] = 0.f;

#pragma unroll
    for (int rg = 0; rg < 2; ++rg) {
#pragma unroll
        for (int r = 0; r < 4; ++r) {
            int rr = w * 32 + rg * 16 + l4 * 4 + r;
            int cr = crow[rg][r];
            float z = 0.f, ns = 0.f, p1 = 0.f;
#pragma unroll
            for (int cf = 0; cf < 8; ++cf) {
                int cc = cf * 16 + l15;
                float tt = fmaf((float)acc[rg][cf][r], QS2L, -SHIFTL);
                float e = exp2f(tt);
                bool same = (cr == ccv[cf]);
                bool dg   = diagblk && (rr == cc);
                if (!same) { z += e; cq[cf][0] += e; }
                else if (!dg) { ns += tt; p1 += e; cq[cf][1] += tt; cq[cf][2] += e; }
            }
#pragma unroll
            for (int m = 1; m < 16; m <<= 1) {
                z  += __shfl_xor(z,  m, 16);
                ns += __shfl_xor(ns, m, 16);
                p1 += __shfl_xor(p1, m, 16);
            }
            if (l15 == 0) {
                redr[rr * 3 + 0] = z;
                redr[rr * 3 + 1] = ns;
                redr[rr * 3 + 2] = p1;
            }
        }
    }
    if (!diagblk) {
#pragma unroll
        for (int cf = 0; cf < 8; ++cf) {
            float z = cq[cf][0], nsv = cq[cf][1], p = cq[cf][2];
            z += __shfl_xor(z, 16, 64);  z += __shfl_xor(z, 32, 64);
            nsv += __shfl_xor(nsv, 16, 64); nsv += __shfl_xor(nsv, 32, 64);
            p += __shfl_xor(p, 16, 64);  p += __shfl_xor(p, 32, 64);
            if (l4 == 0) {
                float* pp = &redc[(w * 128 + cf * 16 + l15) * 3];
                pp[0] = z; pp[1] = nsv; pp[2] = p;
            }
        }
    }
    __syncthreads();

    if (tid < BT) {                           // row-side partials, slot = bj
#pragma unroll
        for (int q = 0; q < 3; ++q)
            Zpart[q * QS + (size_t)bj * n + row0 + tid] = redr[tid * 3 + q];
    } else if (!diagblk) {                    // col-side partials, slot = bi
        int cc = tid - BT;
#pragma unroll
        for (int q = 0; q < 3; ++q)
            Zpart[q * QS + (size_t)bi * n + c0 + cc] =
                redc[(0 * 128 + cc) * 3 + q] + redc[(1 * 128 + cc) * 3 + q] +
                redc[(2 * 128 + cc) * 3 + q] + redc[(3 * 128 + cc) * 3 + q];
    }
}

// ---------------- K3: per-row terms -> per-block (loss,cnt) partials ------
__global__ void k_rowterms(const float* __restrict__ Zpart,
                           const int* __restrict__ classes,
                           const int* __restrict__ hist,
                           float* __restrict__ partial, int n) {
    const int tid = threadIdx.x;
    const int i   = blockIdx.x * 128 + tid;
    const size_t QS = (size_t)64 * n;
    float z = 0.f, ns = 0.f, p1 = 0.f;
    for (int s = 0; s < 64; ++s) {
        size_t o = (size_t)s * n + i;
        z  += Zpart[o];
        ns += Zpart[QS + o];
        p1 += Zpart[2 * QS + o];
    }
    float c    = (float)(hist[classes[i] & 127] - 1);
    float loss = -ns * LN2 + c * logf(z) + p1 / z;   // ns was in log2 units

    __shared__ float sl[2], sc[2];
    float L = loss, C = c;
#pragma unroll
    for (int m = 1; m < 64; m <<= 1) {
        L += __shfl_xor(L, m, 64);
        C += __shfl_xor(C, m, 64);
    }
    if ((tid & 63) == 0) { sl[tid >> 6] = L; sc[tid >> 6] = C; }
    __syncthreads();
    if (tid == 0) {
        partial[blockIdx.x * 2]     = sl[0] + sl[1];
        partial[blockIdx.x * 2 + 1] = sc[0] + sc[1];
    }
}

// ---------------- K4: final reduction of 64 partial pairs ----------------
__global__ void k_final(const float* __restrict__ partial,
                        float* __restrict__ out) {
    int lane = threadIdx.x;                   // one wave
    float L = partial[lane * 2];
    float C = partial[lane * 2 + 1];
#pragma unroll
    for (int m = 1; m < 64; m <<= 1) {
        L += __shfl_xor(L, m, 64);
        C += __shfl_xor(C, m, 64);
    }
    if (lane == 0) out[0] = (C > 0.f) ? L / C : 0.f;
}

extern "C" void kernel_launch(void* const* d_in, const int* in_sizes, int n_in,
                              void* d_out, int out_size, void* d_ws, size_t ws_size,
                              hipStream_t stream) {
    const float* emb     = (const float*)d_in[0];
    const int*   classes = (const int*)d_in[1];
    float*       out     = (float*)d_out;
    const int n  = in_sizes[1];               // 8192
    const int nb = n / BT;                    // 64
    const int npairs = nb * (nb + 1) / 2;     // 2080

    uchar*  normed  = (uchar*)d_ws;                                    // 4 MB
    float*  Zpart   = (float*)((char*)d_ws + (size_t)n * D);           // 6 MB
    float*  partial = Zpart + (size_t)3 * 64 * n;                      // 128 floats
    int*    hist    = (int*)(partial + 128);                           // 512 B

    k_normalize<<<n / 4, 256, 0, stream>>>(emb, classes, normed, hist, n);
    k_zgemm<<<npairs, 256, 0, stream>>>(normed, classes, Zpart, n, nb, npairs);
    k_rowterms<<<n / 128, 128, 0, stream>>>(Zpart, classes, hist, partial, n);
    k_final<<<1, 64, 0, stream>>>(partial, out);
}